// Round 1
// baseline (1266.803 us; speedup 1.0000x reference)
//
#include <hip/hip_runtime.h>
#include <hip/hip_bf16.h>
#include <cstdint>
#include <cstddef>

constexpr int Nn = 4096;
constexpr float LRA = 0.2f;   // leaky relu slope

typedef __attribute__((ext_vector_type(8))) short bf16x8;
typedef __attribute__((ext_vector_type(4))) float f32x4;

__device__ __forceinline__ unsigned short f2bf(float x) {
  union { float f; unsigned u; } v; v.f = x;
  unsigned r = v.u + 0x7FFFu + ((v.u >> 16) & 1u);
  return (unsigned short)(r >> 16);
}
__device__ __forceinline__ float bf2f(unsigned short b) {
  union { unsigned u; float f; } v; v.u = ((unsigned)b) << 16; return v.f;
}

// h = prev[N,din] @ W[din,64]; writes htr (bf16, transposed [64][N]) and
// f1 = h@av[:64], f2 = h@av[64:]. One wave per row (lane == output dim).
__global__ __launch_bounds__(256) void k_hf(
    const float* __restrict__ prev, int din,
    const float* __restrict__ W, const float* __restrict__ av,
    unsigned short* __restrict__ htr,
    float* __restrict__ f1, float* __restrict__ f2) {
  __shared__ float Wl[64 * 64];  // 16KB, staged in 64-row chunks
  int t = threadIdx.x;
  int r = blockIdx.x * 4 + (t >> 6);
  int d = t & 63;
  const float* pr = prev + (size_t)r * din;
  float acc = 0.f;
  for (int kb = 0; kb < din; kb += 64) {
    for (int i = t; i < 64 * 64; i += 256) Wl[i] = W[kb * 64 + i];
    __syncthreads();
    #pragma unroll 8
    for (int k = 0; k < 64; ++k) acc = fmaf(pr[kb + k], Wl[k * 64 + d], acc);
    __syncthreads();
  }
  htr[(size_t)d * Nn + r] = f2bf(acc);
  float p1 = acc * av[d];
  float p2 = acc * av[64 + d];
  #pragma unroll
  for (int off = 32; off; off >>= 1) {
    p1 += __shfl_down(p1, off);
    p2 += __shfl_down(p2, off);
  }
  if (d == 0) { f1[r] = p1; f2[r] = p2; }
}

// Partial rank counts (descending sort rank of f1, stable by index) and
// partial m[j] = #{k: f1[k] > -f2[j]}, 8-way split over the scan axis.
__global__ __launch_bounds__(256) void k_rankp(
    const float* __restrict__ f1, const float* __restrict__ f2,
    int* __restrict__ rankp, int* __restrict__ mp) {
  __shared__ float fl[Nn];
  int t = threadIdx.x;
  for (int i = t; i < Nn; i += 256) fl[i] = f1[i];
  __syncthreads();
  int tau = blockIdx.x * 256 + t;   // 0..65535
  int item = tau >> 3;              // 0..8191
  int q = tau & 7;
  const float* base = fl + q * 512;
  int cnt = 0;
  if (item < Nn) {
    int k = item;
    float v = fl[k];
    int kb = q * 512;
    #pragma unroll 4
    for (int i = 0; i < 512; ++i) {
      float w = base[i];
      cnt += (w > v || (w == v && (kb + i) < k)) ? 1 : 0;
    }
    rankp[q * Nn + k] = cnt;
  } else {
    int j = item - Nn;
    float thr = -f2[j];
    #pragma unroll 4
    for (int i = 0; i < 512; ++i) cnt += (base[i] > thr) ? 1 : 0;
    mp[q * Nn + j] = cnt;
  }
}

__global__ __launch_bounds__(256) void k_scat(
    const int* __restrict__ rankp, const int* __restrict__ mp,
    int* __restrict__ rankg, int* __restrict__ mj) {
  int id = blockIdx.x * 256 + threadIdx.x;   // 8192 items
  if (id < Nn) {
    int s = 0;
    #pragma unroll
    for (int q = 0; q < 8; ++q) s += rankp[q * Nn + id];
    rankg[id] = s;
  } else {
    int j = id - Nn;
    int s = 0;
    #pragma unroll
    for (int q = 0; q < 8; ++q) s += mp[q * Nn + j];
    mj[j] = s;
  }
}

// One block per row r: scatter adj row into sorted order (LDS), scan,
// evaluate s[r,j] for all j via prefix lookup, row softmax, write bf16 att.
__global__ __launch_bounds__(256) void k_rows(
    const float* __restrict__ adj, const int* __restrict__ rankg,
    const float* __restrict__ f1, const float* __restrict__ f2,
    const int* __restrict__ mj, unsigned short* __restrict__ att) {
  __shared__ float P0[Nn];
  __shared__ float P1[Nn];
  __shared__ float red[32];
  int t = threadIdx.x;
  int lane = t & 63;
  int wv = t >> 6;
  int r = blockIdx.x;
  const float* arow = adj + (size_t)r * Nn;
  // coalesced read, scatter into sorted position
  #pragma unroll
  for (int i = 0; i < 16; ++i) {
    int k = i * 256 + t;
    float a = arow[k];
    int rk = rankg[k];
    P0[rk] = a;
    P1[rk] = a * f1[k];
  }
  __syncthreads();
  // inclusive scan of P0/P1 (thread-local 16 + block scan of totals)
  int base = t * 16;
  float a0[16], a1[16];
  #pragma unroll
  for (int i = 0; i < 16; ++i) { a0[i] = P0[base + i]; a1[i] = P1[base + i]; }
  #pragma unroll
  for (int i = 1; i < 16; ++i) { a0[i] += a0[i - 1]; a1[i] += a1[i - 1]; }
  float t0 = a0[15], t1 = a1[15];
  float s0 = t0, s1 = t1;
  #pragma unroll
  for (int off = 1; off < 64; off <<= 1) {
    float u0 = __shfl_up(s0, off);
    float u1 = __shfl_up(s1, off);
    if (lane >= off) { s0 += u0; s1 += u1; }
  }
  if (lane == 63) { red[wv] = s0; red[8 + wv] = s1; }
  __syncthreads();
  float w0 = 0.f, w1 = 0.f;
  for (int i = 0; i < wv; ++i) { w0 += red[i]; w1 += red[8 + i]; }
  float ex0 = (s0 - t0) + w0;
  float ex1 = (s1 - t1) + w1;
  #pragma unroll
  for (int i = 0; i < 16; ++i) { P0[base + i] = a0[i] + ex0; P1[base + i] = a1[i] + ex1; }
  __syncthreads();
  float S0 = P0[Nn - 1], S1 = P1[Nn - 1];
  // s-pass: s[r,j] = a*(S1 + f2j*S0) + (1-a)*(P1[m-1] + f2j*P0[m-1])
  float sv[16];
  float mx = -3.0e38f;
  #pragma unroll
  for (int c = 0; c < 16; ++c) {
    int j = c * 256 + t;
    int mm = mj[j];
    float fj = f2[j];
    float pr0 = (mm > 0) ? P0[mm - 1] : 0.f;
    float pr1 = (mm > 0) ? P1[mm - 1] : 0.f;
    float s = LRA * fmaf(fj, S0, S1) + (1.f - LRA) * fmaf(fj, pr0, pr1);
    sv[c] = s;
    mx = fmaxf(mx, s);
  }
  #pragma unroll
  for (int off = 32; off; off >>= 1) mx = fmaxf(mx, __shfl_xor(mx, off));
  __syncthreads();   // red reuse fence
  if (lane == 0) red[wv] = mx;
  __syncthreads();
  mx = fmaxf(fmaxf(red[0], red[1]), fmaxf(red[2], red[3]));
  float pv[16];
  float sum = 0.f;
  #pragma unroll
  for (int c = 0; c < 16; ++c) { float p = __expf(sv[c] - mx); pv[c] = p; sum += p; }
  #pragma unroll
  for (int off = 32; off; off >>= 1) sum += __shfl_xor(sum, off);
  if (lane == 0) red[8 + wv] = sum;
  __syncthreads();
  float inv = 1.f / (red[8] + red[9] + red[10] + red[11]);
  unsigned short* orow = att + (size_t)r * Nn;
  #pragma unroll
  for (int c = 0; c < 16; ++c) orow[c * 256 + t] = f2bf(pv[c] * inv);
}

// C[4096,NC] = A[4096,4096] @ B ; B given transposed bf16 [NC][4096].
// AMODE 0: A is bf16; 1: A f32 -> bf16; 2: A f32 split hi/lo (3-MFMA).
// Split-K=8 into Cpart[kc][4096][NC].
template<int AMODE, int NC, bool BSPLIT>
__global__ __launch_bounds__(256) void k_gemm(
    const void* __restrict__ Ap,
    const unsigned short* __restrict__ Bth,
    const unsigned short* __restrict__ Btl,
    float* __restrict__ Cpart) {
  constexpr int NT = NC / 16;
  int t = threadIdx.x;
  int wv = t >> 6, l = t & 63;
  int l15 = l & 15, lq = l >> 4;
  int row0 = blockIdx.x * 64 + wv * 16;
  int kc = blockIdx.y;
  f32x4 acc[NT];
  #pragma unroll
  for (int i = 0; i < NT; ++i) acc[i] = (f32x4){0.f, 0.f, 0.f, 0.f};
  int row = row0 + l15;
  int kb = kc * 512 + lq * 8;
  for (int k0 = 0; k0 < 512; k0 += 32) {
    int k = kb + k0;
    bf16x8 af, af2;
    if constexpr (AMODE == 0) {
      af = *(const bf16x8*)((const unsigned short*)Ap + (size_t)row * Nn + k);
    } else {
      const float* fp = (const float*)Ap + (size_t)row * Nn + k;
      const float4 xa = *(const float4*)fp;
      const float4 xb = *(const float4*)(fp + 4);
      float xs[8] = {xa.x, xa.y, xa.z, xa.w, xb.x, xb.y, xb.z, xb.w};
      #pragma unroll
      for (int i = 0; i < 8; ++i) {
        unsigned short hb = f2bf(xs[i]);
        ((unsigned short*)&af)[i] = hb;
        if constexpr (AMODE == 2)
          ((unsigned short*)&af2)[i] = f2bf(xs[i] - bf2f(hb));
      }
    }
    #pragma unroll
    for (int ct = 0; ct < NT; ++ct) {
      bf16x8 bh = *(const bf16x8*)(Bth + (size_t)(ct * 16 + l15) * Nn + k);
      acc[ct] = __builtin_amdgcn_mfma_f32_16x16x32_bf16(af, bh, acc[ct], 0, 0, 0);
      if constexpr (BSPLIT) {
        bf16x8 bl = *(const bf16x8*)(Btl + (size_t)(ct * 16 + l15) * Nn + k);
        acc[ct] = __builtin_amdgcn_mfma_f32_16x16x32_bf16(af, bl, acc[ct], 0, 0, 0);
      }
      if constexpr (AMODE == 2)
        acc[ct] = __builtin_amdgcn_mfma_f32_16x16x32_bf16(af2, bh, acc[ct], 0, 0, 0);
    }
  }
  // D layout (m89-verified): col = lane&15, row = 4*(lane>>4)+reg
  #pragma unroll
  for (int ct = 0; ct < NT; ++ct) {
    #pragma unroll
    for (int q = 0; q < 4; ++q) {
      int rr = row0 + lq * 4 + q;
      int cc = ct * 16 + l15;
      Cpart[((size_t)kc * Nn + rr) * NC + cc] = acc[ct][q];
    }
  }
}

// sum split-K partials + epilogue (0 none, 1 elu, 2 relu), strided dst write
template<int NC>
__global__ __launch_bounds__(256) void k_red(
    const float* __restrict__ Cpart, float* __restrict__ dst,
    int ldd, int coff, int epi) {
  int id = blockIdx.x * 256 + threadIdx.x;
  int r = id / NC, c = id % NC;
  float s = 0.f;
  #pragma unroll
  for (int kc = 0; kc < 8; ++kc) s += Cpart[((size_t)kc * Nn + r) * NC + c];
  if (epi == 1) s = (s > 0.f) ? s : expm1f(s);
  else if (epi == 2) s = fmaxf(s, 0.f);
  dst[(size_t)r * ldd + coff + c] = s;
}

// f32 [N,nc] -> transposed bf16 hi/lo planes [nc][N]
__global__ __launch_bounds__(256) void k_bt(
    const float* __restrict__ in, int nc,
    unsigned short* __restrict__ oh, unsigned short* __restrict__ ol) {
  int id = blockIdx.x * 256 + threadIdx.x;
  int r = id / nc, c = id % nc;
  float v = in[id];
  unsigned short hb = f2bf(v);
  oh[(size_t)c * Nn + r] = hb;
  ol[(size_t)c * Nn + r] = f2bf(v - bf2f(hb));
}

// u = h1[N,64] @ l2w[64,32], written directly as transposed bf16 [32][N]
__global__ __launch_bounds__(256) void k_u(
    const float* __restrict__ h1, const float* __restrict__ W,
    unsigned short* __restrict__ ut) {
  __shared__ float Wl[64 * 32];
  int t = threadIdx.x;
  for (int i = t; i < 64 * 32; i += 256) Wl[i] = W[i];
  __syncthreads();
  int id = blockIdx.x * 256 + t;
  int r = id >> 5, d = id & 31;
  const float* pr = h1 + (size_t)r * 64;
  float acc = 0.f;
  #pragma unroll 8
  for (int k = 0; k < 64; ++k) acc = fmaf(pr[k], Wl[k * 32 + d], acc);
  ut[(size_t)d * Nn + r] = f2bf(acc);
}

extern "C" void kernel_launch(void* const* d_in, const int* in_sizes, int n_in,
                              void* d_out, int out_size, void* d_ws, size_t ws_size,
                              hipStream_t stream) {
  (void)in_sizes; (void)n_in; (void)out_size; (void)ws_size;
  const float* x    = (const float*)d_in[0];
  const float* adj  = (const float*)d_in[1];
  const float* wini = (const float*)d_in[2];
  const float* hH   = (const float*)d_in[3];
  const float* ha   = (const float*)d_in[4];
  const float* oH   = (const float*)d_in[5];
  const float* oa   = (const float*)d_in[6];
  const float* l2w  = (const float*)d_in[7];

  char* ws = (char*)d_ws;
  size_t off = 0;
  auto alloc = [&](size_t bytes) -> void* {
    void* p = ws + off;
    off += (bytes + 4095) & ~(size_t)4095;
    return p;
  };
  unsigned short* htr  = (unsigned short*)alloc((size_t)Nn * 64 * 2);
  float* f1            = (float*)alloc(Nn * 4);
  float* f2            = (float*)alloc(Nn * 4);
  int* rankg           = (int*)alloc(Nn * 4);
  int* mj              = (int*)alloc(Nn * 4);
  int* rankp           = (int*)alloc(8 * Nn * 4);
  int* mp              = (int*)alloc(8 * Nn * 4);
  unsigned short* att  = (unsigned short*)alloc((size_t)Nn * Nn * 2);   // 32MB
  float* cat           = (float*)alloc((size_t)Nn * 256 * 4);           // 4MB
  float* x1            = (float*)alloc((size_t)Nn * 64 * 4);
  unsigned short* bth  = (unsigned short*)alloc((size_t)Nn * 64 * 2);
  unsigned short* btl  = (unsigned short*)alloc((size_t)Nn * 64 * 2);
  float* t0b           = (float*)alloc((size_t)Nn * 64 * 4);
  float* h1b           = (float*)alloc((size_t)Nn * 64 * 4);
  float* cpart         = (float*)alloc(8 * (size_t)Nn * 64 * 4);        // 8MB

  auto run_gat = [&](const float* xin, int din, const float* Hm, const float* av,
                     const float* adj_c, float* dst, int ldd, int coff) {
    k_hf<<<dim3(Nn / 4), 256, 0, stream>>>(xin, din, Hm, av, htr, f1, f2);
    k_rankp<<<dim3(256), 256, 0, stream>>>(f1, f2, rankp, mp);
    k_scat<<<dim3(32), 256, 0, stream>>>(rankp, mp, rankg, mj);
    k_rows<<<dim3(Nn), 256, 0, stream>>>(adj_c, rankg, f1, f2, mj, att);
    k_gemm<0, 64, false><<<dim3(64, 8), 256, 0, stream>>>(att, htr, nullptr, cpart);
    k_red<64><<<dim3(Nn * 64 / 256), 256, 0, stream>>>(cpart, dst, ldd, coff, 1);
  };

  const float* prev = wini;
  for (int cell = 0; cell < 2; ++cell) {
    const float* adj_c = adj + (size_t)cell * Nn * Nn;
    for (int hd = 0; hd < 4; ++hd) {
      run_gat(prev, 64, hH + (size_t)(cell * 4 + hd) * 64 * 64,
              ha + (size_t)(cell * 4 + hd) * 128, adj_c, cat, 256, hd * 64);
    }
    run_gat(cat, 256, oH + (size_t)cell * 256 * 64, oa + (size_t)cell * 128,
            adj_c, x1, 64, 0);
    prev = x1;
  }

  // tail, cell 1 only (h1/h2 of cell 0 are dead in the reference)
  const float* adj1 = adj + (size_t)Nn * Nn;
  const float* x1c  = x + (size_t)Nn * Nn;
  k_bt<<<dim3(Nn * 64 / 256), 256, 0, stream>>>(x1, 64, bth, btl);
  k_gemm<2, 64, true><<<dim3(64, 8), 256, 0, stream>>>(x1c, bth, btl, cpart);
  k_red<64><<<dim3(Nn * 64 / 256), 256, 0, stream>>>(cpart, t0b, 64, 0, 0);
  k_bt<<<dim3(Nn * 64 / 256), 256, 0, stream>>>(t0b, 64, bth, btl);
  k_gemm<1, 64, false><<<dim3(64, 8), 256, 0, stream>>>(adj1, bth, nullptr, cpart);
  k_red<64><<<dim3(Nn * 64 / 256), 256, 0, stream>>>(cpart, h1b, 64, 0, 2);
  k_u<<<dim3(Nn * 32 / 256), 256, 0, stream>>>(h1b, l2w + 64 * 32, bth);
  k_gemm<1, 32, false><<<dim3(64, 8), 256, 0, stream>>>(adj1, bth, nullptr, cpart);
  k_red<32><<<dim3(Nn * 32 / 256), 256, 0, stream>>>(cpart, (float*)d_out, 32, 0, 0);
}